// Round 3
// baseline (431.124 us; speedup 1.0000x reference)
//
#include <hip/hip_runtime.h>
#include <math.h>

// RX rotation gate on qubit TARGET=10 of N_QUBITS=24, batch=2.
// state layout: [DIM, batch] row-major == [a(2^10), j(2), c(2^13), b(2)].
// out: [2, DIM, batch] (re block then im block).
//
// out_re[a,j,c,b] = cos_b * re[a,j,c,b]   + sin_b * im[a,1-j,c,b]
// out_im[a,j,c,b] = cos_b * im[a,j,c,b]   - sin_b * re[a,1-j,c,b]
// with cos_b = cos(theta_b/2), sin_b = sin(theta_b/2).

#define RG_DIM   (1 << 24)
#define RG_RIGHT (1 << 13)   // 2^(24-10-1)
#define RG_BATCH 2
// floats per (a, j) inner block = RIGHT*BATCH = 16384 -> 4096 float4
#define RG_INNER4_LOG2 12
#define RG_INNER4 (1 << RG_INNER4_LOG2)
// total float4-pairs to process = DIM*BATCH/2 floats / 4 = 4,194,304
#define RG_TOTAL4 ((long long)RG_DIM * RG_BATCH / 8)

__global__ __launch_bounds__(256)
void rx_gate_kernel(const float* __restrict__ state_re,
                    const float* __restrict__ state_im,
                    const float* __restrict__ thetas,
                    float* __restrict__ out)
{
    float s0, c0, s1, c1;
    sincosf(thetas[0] * 0.5f, &s0, &c0);
    sincosf(thetas[1] * 0.5f, &s1, &c1);

    const float4* re = (const float4*)state_re;
    const float4* im = (const float4*)state_im;
    float4* out_re = (float4*)out;
    float4* out_im = (float4*)(out + (size_t)RG_DIM * RG_BATCH);

    const long long stride = (long long)gridDim.x * blockDim.x;
    for (long long v = (long long)blockIdx.x * blockDim.x + threadIdx.x;
         v < RG_TOTAL4; v += stride)
    {
        long long a     = v >> RG_INNER4_LOG2;
        long long inner = v & (RG_INNER4 - 1);
        long long i0 = (a << (RG_INNER4_LOG2 + 1)) + inner;  // j=0 slot
        long long i1 = i0 + RG_INNER4;                       // j=1 slot

        float4 r0 = re[i0];
        float4 r1 = re[i1];
        float4 m0 = im[i0];
        float4 m1 = im[i1];

        float4 or0, or1, om0, om1;
        // components .x/.z -> batch 0 ; .y/.w -> batch 1
        or0.x = c0 * r0.x + s0 * m1.x;
        or0.y = c1 * r0.y + s1 * m1.y;
        or0.z = c0 * r0.z + s0 * m1.z;
        or0.w = c1 * r0.w + s1 * m1.w;

        or1.x = c0 * r1.x + s0 * m0.x;
        or1.y = c1 * r1.y + s1 * m0.y;
        or1.z = c0 * r1.z + s0 * m0.z;
        or1.w = c1 * r1.w + s1 * m0.w;

        om0.x = c0 * m0.x - s0 * r1.x;
        om0.y = c1 * m0.y - s1 * r1.y;
        om0.z = c0 * m0.z - s0 * r1.z;
        om0.w = c1 * m0.w - s1 * r1.w;

        om1.x = c0 * m1.x - s0 * r0.x;
        om1.y = c1 * m1.y - s1 * r0.y;
        om1.z = c0 * m1.z - s0 * r0.z;
        om1.w = c1 * m1.w - s1 * r0.w;

        out_re[i0] = or0;
        out_re[i1] = or1;
        out_im[i0] = om0;
        out_im[i1] = om1;
    }
}

extern "C" void kernel_launch(void* const* d_in, const int* in_sizes, int n_in,
                              void* d_out, int out_size, void* d_ws, size_t ws_size,
                              hipStream_t stream)
{
    const float* state_re = (const float*)d_in[0];
    const float* state_im = (const float*)d_in[1];
    const float* thetas   = (const float*)d_in[2];
    float* out = (float*)d_out;

    // memory-bound streaming: ~2048 blocks, grid-stride the rest
    const int block = 256;
    const int grid = 2048;
    rx_gate_kernel<<<grid, block, 0, stream>>>(state_re, state_im, thetas, out);
}

// Round 6
// 417.355 us; speedup vs baseline: 1.0330x; 1.0330x over previous
//
#include <hip/hip_runtime.h>
#include <math.h>

// RX rotation gate on qubit TARGET=10 of N_QUBITS=24, batch=2.
// state layout: [DIM, batch] row-major == [a(2^10), j(2), c(2^13), b(2)].
// out: [2, DIM, batch] (re block then im block).
//
// out_re[a,j,c,b] = cos_b * re[a,j,c,b] + sin_b * im[a,1-j,c,b]
// out_im[a,j,c,b] = cos_b * im[a,j,c,b] - sin_b * re[a,1-j,c,b]
// with cos_b = cos(theta_b/2), sin_b = sin(theta_b/2).
//
// Streaming roofline: 268 MB read + 268 MB write ~= 84 us @ 6.4 TB/s.
// R3 evidence: kernel dispatch < 163 us (absent from rocprof top-5);
// bench dur_us 431 is dominated by ~333 us of harness 1-GiB poison fills.

#define RG_DIM   (1 << 24)
#define RG_BATCH 2
#define RG_INNER4_LOG2 12              // float4 elems per (a,j) block = 2^13 * 2 / 4
#define RG_INNER4 (1 << RG_INNER4_LOG2)
#define RG_TOTAL4 (RG_DIM * RG_BATCH / 8)   // 4,194,304 float4-pairs (fits int)

typedef float f32x4 __attribute__((ext_vector_type(4)));

__global__ __launch_bounds__(256)
void rx_gate_kernel(const float* __restrict__ state_re,
                    const float* __restrict__ state_im,
                    const float* __restrict__ thetas,
                    float* __restrict__ out)
{
    float s0, c0, s1, c1;
    __sincosf(thetas[0] * 0.5f, &s0, &c0);
    __sincosf(thetas[1] * 0.5f, &s1, &c1);

    const f32x4* re = (const f32x4*)state_re;
    const f32x4* im = (const f32x4*)state_im;
    f32x4* out_re = (f32x4*)out;
    f32x4* out_im = (f32x4*)(out + (size_t)RG_DIM * RG_BATCH);

    const int stride = gridDim.x * blockDim.x;     // 524288 -> exactly 8 iters/thread
    for (int v = blockIdx.x * blockDim.x + threadIdx.x; v < RG_TOTAL4; v += stride)
    {
        int a     = v >> RG_INNER4_LOG2;
        int inner = v & (RG_INNER4 - 1);
        int i0 = (a << (RG_INNER4_LOG2 + 1)) + inner;  // j=0 slot (max ~2^23)
        int i1 = i0 + RG_INNER4;                       // j=1 slot

        f32x4 r0 = __builtin_nontemporal_load(&re[i0]);
        f32x4 r1 = __builtin_nontemporal_load(&re[i1]);
        f32x4 m0 = __builtin_nontemporal_load(&im[i0]);
        f32x4 m1 = __builtin_nontemporal_load(&im[i1]);

        f32x4 or0, or1, om0, om1;
        // lanes .x/.z -> batch 0 (c0,s0); lanes .y/.w -> batch 1 (c1,s1)
        or0.x = c0 * r0.x + s0 * m1.x;
        or0.y = c1 * r0.y + s1 * m1.y;
        or0.z = c0 * r0.z + s0 * m1.z;
        or0.w = c1 * r0.w + s1 * m1.w;

        or1.x = c0 * r1.x + s0 * m0.x;
        or1.y = c1 * r1.y + s1 * m0.y;
        or1.z = c0 * r1.z + s0 * m0.z;
        or1.w = c1 * r1.w + s1 * m0.w;

        om0.x = c0 * m0.x - s0 * r1.x;
        om0.y = c1 * m0.y - s1 * r1.y;
        om0.z = c0 * m0.z - s0 * r1.z;
        om0.w = c1 * m0.w - s1 * r1.w;

        om1.x = c0 * m1.x - s0 * r0.x;
        om1.y = c1 * m1.y - s1 * r0.y;
        om1.z = c0 * m1.z - s0 * r0.z;
        om1.w = c1 * m1.w - s1 * r0.w;

        __builtin_nontemporal_store(or0, &out_re[i0]);
        __builtin_nontemporal_store(or1, &out_re[i1]);
        __builtin_nontemporal_store(om0, &out_im[i0]);
        __builtin_nontemporal_store(om1, &out_im[i1]);
    }
}

extern "C" void kernel_launch(void* const* d_in, const int* in_sizes, int n_in,
                              void* d_out, int out_size, void* d_ws, size_t ws_size,
                              hipStream_t stream)
{
    const float* state_re = (const float*)d_in[0];
    const float* state_im = (const float*)d_in[1];
    const float* thetas   = (const float*)d_in[2];
    float* out = (float*)d_out;

    // 2048 blocks x 256 threads = 8 blocks/CU on 256 CUs (full 32-wave occupancy),
    // exactly 8 grid-stride iterations per thread.
    rx_gate_kernel<<<2048, 256, 0, stream>>>(state_re, state_im, thetas, out);
}